// Round 15
// baseline (1437.319 us; speedup 1.0000x reference)
//
#include <hip/hip_runtime.h>
#include <hip/hip_cooperative_groups.h>
#include <math.h>

namespace cg = cooperative_groups;

#define LR_C 0.1f
#define WINDOW_C 10
#define NH 512
#define WAVE 64
#define ALPHA (-1.44269504088896340736f)  // -log2(e)
#define NSEG 250
#define KSWEEPS 12   // calibration: K=8 -> 0.109, K=12 -> 0.0078 (NSEG=250)

typedef _Float16 half_t;
typedef __fp16 fp16x2_t __attribute__((ext_vector_type(2)));

__device__ __forceinline__ void gld_lds16(const void* g, void* l) {
    __builtin_amdgcn_global_load_lds((const __attribute__((address_space(1))) void*)g,
                                     (__attribute__((address_space(3))) void*)l, 16, 0, 0);
}
__device__ __forceinline__ void gld_lds4(const void* g, void* l) {
    __builtin_amdgcn_global_load_lds((const __attribute__((address_space(1))) void*)g,
                                     (__attribute__((address_space(3))) void*)l, 4, 0, 0);
}
__device__ __forceinline__ unsigned pack_h2(float a, float b) {
    union { fp16x2_t h; unsigned u; } c;
    c.h = __builtin_amdgcn_cvt_pkrtz(a, b);
    return c.u;
}
__device__ __forceinline__ unsigned pkadd(unsigned a, unsigned b) {
    union { fp16x2_t h; unsigned u; } x, y;
    x.u = a; y.u = b;
    x.h = x.h + y.h;   // v_pk_add_f16
    return x.u;
}
__device__ __forceinline__ float lo_h(unsigned u) {
    union { unsigned short s; half_t h; } c; c.s = (unsigned short)(u & 0xffffu);
    return (float)c.h;
}
__device__ __forceinline__ float hi_h(unsigned u) {
    union { unsigned short s; half_t h; } c; c.s = (unsigned short)(u >> 16);
    return (float)c.h;
}

// Scaled space: W = ALPHA*w, y_t = W[t]·x_t, h_t = 1/(1+2^{y_t}),
// W[t+1] = W[t] + h_t*cx_t,  cx_t = ALPHA*LR*r_t*x_t.
// Lookahead: y_{t+1} = u_t + h_t*d_t,  u_t = W[t]·x_{t+1},  d_t = cx_t·x_{t+1}.
__global__ void prep_kernel(const float* __restrict__ X,
                            const float* __restrict__ rewards,
                            float4* __restrict__ pk, float* __restrict__ dv,
                            int T, int Talloc) {
    int t = blockIdx.x * blockDim.x + threadIdx.x;
    if (t >= Talloc) return;
    if (t >= T) { pk[t] = make_float4(0.f, 0.f, 0.f, 0.f); dv[t] = 0.f; return; }
    int lo = t - (WINDOW_C - 1); if (lo < 0) lo = 0;
    float s = 0.0f;
    for (int k = lo; k <= t; ++k) s += rewards[k];
    float r = rewards[t] - s / (float)(t - lo + 1);
    float c = ALPHA * LR_C * r;
    float cx0 = c * X[2 * t];
    float cx1 = c * X[2 * t + 1];
    float xn0 = 0.0f, xn1 = 0.0f;
    if (t + 1 < T) { xn0 = X[2 * t + 2]; xn1 = X[2 * t + 3]; }
    pk[t] = make_float4(xn0, xn1, cx0, cx1);
    dv[t] = fmaf(cx1, xn1, cx0 * xn0);
}

// One parareal sweep for (segment s, half): prefix from Dread (coalesced
// interleaved [sp][unit] float2 layout), fine propagation from LDS operands,
// then OUT=0: delta write / OUT=1: packed-fp16 wave reduction to partialU.
template <int OUT>
__device__ __forceinline__ void sweep_body(
    int s, int half, int tid, const float4* __restrict__ lpk,
    const float* __restrict__ ldv, float Wb0, float Wb1,
    const float* __restrict__ Dread, float* __restrict__ Dwrite,
    int sweep, int L, unsigned* __restrict__ partialU,
    float x0, float x1, int TW2) {
    const int unit = half * 256 + tid;
    const int lane = tid & 63;
    const int wv   = tid >> 6;
    const int t0   = s * L;

    float W0 = Wb0, W1 = Wb1;
    if (sweep > 0) {
        const float2* dp = (const float2*)Dread;
        float acc0[8], acc1[8];
        #pragma unroll
        for (int j = 0; j < 8; ++j) { acc0[j] = 0.f; acc1[j] = 0.f; }
        int sp = 0;
        for (; sp + 32 <= s; sp += 32) {   // 32 independent coalesced loads
            float2 v[32];
            #pragma unroll
            for (int j = 0; j < 32; ++j) v[j] = dp[(size_t)(sp + j) * NH + unit];
            #pragma unroll
            for (int j = 0; j < 32; ++j) { acc0[j & 7] += v[j].x; acc1[j & 7] += v[j].y; }
        }
        for (; sp + 8 <= s; sp += 8) {
            float2 v[8];
            #pragma unroll
            for (int j = 0; j < 8; ++j) v[j] = dp[(size_t)(sp + j) * NH + unit];
            #pragma unroll
            for (int j = 0; j < 8; ++j) { acc0[j] += v[j].x; acc1[j] += v[j].y; }
        }
        for (; sp < s; ++sp) {
            float2 v = dp[(size_t)sp * NH + unit];
            acc0[0] += v.x; acc1[0] += v.y;
        }
        float t00 = 0.f, t01 = 0.f;
        #pragma unroll
        for (int j = 0; j < 8; ++j) { t00 += acc0[j]; t01 += acc1[j]; }
        W0 += t00; W1 += t01;
    }
    const float Wi0 = W0, Wi1 = W1;

    float u = fmaf(W1, x1, W0 * x0);     // y at segment-local t=0
    float h = 0.f, dpv = 0.f, cxp0 = 0.f, cxp1 = 0.f;
    const int prow = half * 4 + wv;      // 0..7
    float4 pA[8], pB[8], dA[2], dB[2];
    float hh[8];

#define BODY(Pq, Dq, TT)                                                      \
    {                                                                         \
        _Pragma("unroll")                                                     \
        for (int j = 0; j < 8; ++j) {                                         \
            float y = fmaf(h, dpv, u);                                        \
            W0 = fmaf(h, cxp0, W0);                                           \
            W1 = fmaf(h, cxp1, W1);                                           \
            u = fmaf(W1, Pq[j].y, W0 * Pq[j].x);                              \
            float e = __builtin_amdgcn_exp2f(y);                              \
            h = __builtin_amdgcn_rcpf(1.0f + e);                              \
            hh[j] = h;                                                        \
            cxp0 = Pq[j].z; cxp1 = Pq[j].w; dpv = Dq[j >> 2][j & 3];          \
        }                                                                     \
        if (OUT) {                                                            \
            unsigned pku[4];                                                  \
            _Pragma("unroll")                                                 \
            for (int q = 0; q < 4; ++q)                                       \
                pku[q] = pack_h2(hh[2 * q], hh[2 * q + 1]);                   \
            _Pragma("unroll")                                                 \
            for (int m = 1; m < WAVE; m <<= 1) {                              \
                _Pragma("unroll")                                             \
                for (int q = 0; q < 4; ++q)                                   \
                    pku[q] = pkadd(pku[q], __shfl_xor(pku[q], m, WAVE));      \
            }                                                                 \
            if (lane == 0) {                                                  \
                uint4 st = make_uint4(pku[0], pku[1], pku[2], pku[3]);        \
                *(uint4*)(partialU + (size_t)prow * TW2 + ((t0 + (TT)) >> 1)) = st; \
            }                                                                 \
        }                                                                     \
    }

    #pragma unroll
    for (int j = 0; j < 8; ++j) pA[j] = lpk[j];
    dA[0] = *(const float4*)(ldv);     dA[1] = *(const float4*)(ldv + 4);
    for (int s0 = 0; s0 < L; s0 += 16) {
        #pragma unroll
        for (int j = 0; j < 8; ++j) pB[j] = lpk[s0 + 8 + j];
        dB[0] = *(const float4*)(ldv + s0 + 8); dB[1] = *(const float4*)(ldv + s0 + 12);
        BODY(pA, dA, s0)
        if (s0 + 16 < L) {
            #pragma unroll
            for (int j = 0; j < 8; ++j) pA[j] = lpk[s0 + 16 + j];
            dA[0] = *(const float4*)(ldv + s0 + 16); dA[1] = *(const float4*)(ldv + s0 + 20);
        }
        BODY(pB, dB, s0 + 8)
    }
#undef BODY

    W0 = fmaf(h, cxp0, W0);
    W1 = fmaf(h, cxp1, W1);
    if (!OUT) {
        float2* dw = (float2*)Dwrite;
        dw[(size_t)s * NH + unit] = make_float2(W0 - Wi0, W1 - Wi1);
    }
}

// Fused cooperative kernel: stage once, keep W_init in regs, run all
// correction sweeps + OUT pass with grid.sync() between sweeps.
__global__ __launch_bounds__(256, 2) void coop_kernel(
    const float* __restrict__ Wg, const float* __restrict__ X,
    const float4* __restrict__ pk, const float* __restrict__ dv,
    float* D0, float* D1, unsigned* __restrict__ partialU,
    int L, int Lpad, int T, int TW2) {
    cg::grid_group grid = cg::this_grid();
    extern __shared__ char smem[];
    float4* lpk = (float4*)smem;
    float*  ldv = (float*)(smem + 16 * (size_t)Lpad);
    const int tid  = threadIdx.x;
    const int s    = blockIdx.x >> 1;
    const int half = blockIdx.x & 1;
    const int lane = tid & 63;
    const int wv   = tid >> 6;
    const int t0   = s * L;
    const int unit = half * 256 + tid;

    for (int k = wv; k * 64 < Lpad; k += 4)
        gld_lds16(pk + t0 + k * 64 + lane, lpk + k * 64);
    for (int k = wv; k * 64 < Lpad; k += 4)
        gld_lds4(dv + t0 + k * 64 + lane, ldv + k * 64);

    const float Wb0 = ALPHA * Wg[2 * unit];
    const float Wb1 = ALPHA * Wg[2 * unit + 1];
    float x0 = 0.f, x1 = 0.f;
    if (t0 < T) { x0 = X[2 * t0]; x1 = X[2 * t0 + 1]; }

    __builtin_amdgcn_s_waitcnt(0);
    __syncthreads();

    for (int k = 0; k < KSWEEPS; ++k) {
        const float* Dr = (k & 1) ? D0 : D1;   // k odd reads D0 (k-1 even wrote it)
        float*       Dw = (k & 1) ? D1 : D0;
        sweep_body<0>(s, half, tid, lpk, ldv, Wb0, Wb1, Dr, Dw, k, L,
                      nullptr, x0, x1, TW2);
        __threadfence();
        grid.sync();
    }
    sweep_body<1>(s, half, tid, lpk, ldv, Wb0, Wb1,
                  (KSWEEPS & 1) ? D0 : D1, nullptr, KSWEEPS, L,
                  partialU, x0, x1, TW2);
}

// Fallback (if cooperative launch unavailable): one dispatch per sweep.
template <int OUT>
__global__ __launch_bounds__(256, 2) void sweep_kernel(
    const float* __restrict__ Wg, const float* __restrict__ X,
    const float4* __restrict__ pk, const float* __restrict__ dv,
    const float* __restrict__ Dread, float* __restrict__ Dwrite,
    int sweep, int L, int Lpad, unsigned* __restrict__ partialU,
    int T, int TW2) {
    extern __shared__ char smem[];
    float4* lpk = (float4*)smem;
    float*  ldv = (float*)(smem + 16 * (size_t)Lpad);
    const int tid  = threadIdx.x;
    const int s    = blockIdx.x >> 1;
    const int half = blockIdx.x & 1;
    const int lane = tid & 63;
    const int wv   = tid >> 6;
    const int t0   = s * L;
    const int unit = half * 256 + tid;

    for (int k = wv; k * 64 < Lpad; k += 4)
        gld_lds16(pk + t0 + k * 64 + lane, lpk + k * 64);
    for (int k = wv; k * 64 < Lpad; k += 4)
        gld_lds4(dv + t0 + k * 64 + lane, ldv + k * 64);

    const float Wb0 = ALPHA * Wg[2 * unit];
    const float Wb1 = ALPHA * Wg[2 * unit + 1];
    float x0 = 0.f, x1 = 0.f;
    if (t0 < T) { x0 = X[2 * t0]; x1 = X[2 * t0 + 1]; }

    __builtin_amdgcn_s_waitcnt(0);
    __syncthreads();

    sweep_body<OUT>(s, half, tid, lpk, ldv, Wb0, Wb1, Dread, Dwrite,
                    sweep, L, partialU, x0, x1, TW2);
}

// Unpack + sum the 8 packed partial rows; one thread per t-pair.
__global__ void final_packed(const unsigned* __restrict__ pU,
                             float* __restrict__ out, int T, int TW2) {
    int p = blockIdx.x * blockDim.x + threadIdx.x;
    if (p >= (T + 1) / 2) return;
    float s0 = 0.f, s1 = 0.f;
    #pragma unroll
    for (int r = 0; r < 8; ++r) {
        unsigned v = pU[(size_t)r * TW2 + p];
        s0 += lo_h(v);
        s1 += hi_h(v);
    }
    const float inv = 1.0f / (float)NH;
    out[2 * p] = s0 * inv;
    if (2 * p + 1 < T) out[2 * p + 1] = s1 * inv;
}

extern "C" void kernel_launch(void* const* d_in, const int* in_sizes, int n_in,
                              void* d_out, int out_size, void* d_ws, size_t ws_size,
                              hipStream_t stream) {
    const float* X       = (const float*)d_in[0];
    const float* rewards = (const float*)d_in[1];
    const float* Winit   = (const float*)d_in[2];
    float* out = (float*)d_out;
    const int T = in_sizes[1];

    const int L  = (((T + NSEG - 1) / NSEG) + 15) & ~15;  // seg length, %16==0
    const int TW = NSEG * L;                               // padded horizon
    const int TW2 = TW / 2;                                // t-pairs
    const int Lpad = ((L + 63) >> 6) << 6;                 // staged entries
    const int Talloc = TW + Lpad + 64;                     // staging overrun room

    char* w = (char*)d_ws;
    float4*   pk   = (float4*)w;               w += 16ull * (size_t)Talloc;
    float*    dvp  = (float*)w;                w += 4ull * (size_t)Talloc;
    float*    D0   = (float*)w;                w += 4096ull * NSEG;   // 1 MB
    float*    D1   = (float*)w;                w += 4096ull * NSEG;   // 1 MB
    unsigned* partialU = (unsigned*)w;         // 8 * TW2 u32 (~1.6 MB)

    prep_kernel<<<(Talloc + 255) / 256, 256, 0, stream>>>(X, rewards, pk, dvp, T, Talloc);

    const size_t smem = (size_t)Lpad * 20;  // 16B pk + 4B dv per entry
    int Lv = L, Lpadv = Lpad, Tv = T, TW2v = TW2;
    void* args[] = {(void*)&Winit, (void*)&X, (void*)&pk, (void*)&dvp,
                    (void*)&D0, (void*)&D1, (void*)&partialU,
                    (void*)&Lv, (void*)&Lpadv, (void*)&Tv, (void*)&TW2v};
    hipError_t ce = hipLaunchCooperativeKernel((const void*)coop_kernel,
                                               dim3(2 * NSEG), dim3(256),
                                               args, (unsigned)smem, stream);
    if (ce != hipSuccess) {
        (void)hipGetLastError();   // clear; use per-sweep fallback (same math)
        for (int k = 0; k < KSWEEPS; ++k) {
            const float* Dr = (k & 1) ? D0 : D1;
            float*       Dw = (k & 1) ? D1 : D0;
            sweep_kernel<0><<<2 * NSEG, 256, smem, stream>>>(
                Winit, X, pk, dvp, Dr, Dw, k, L, Lpad, nullptr, T, TW2);
        }
        sweep_kernel<1><<<2 * NSEG, 256, smem, stream>>>(
            Winit, X, pk, dvp, (KSWEEPS & 1) ? D0 : D1, nullptr,
            KSWEEPS, L, Lpad, partialU, T, TW2);
    }

    final_packed<<<((T + 1) / 2 + 255) / 256, 256, 0, stream>>>(partialU, out, T, TW2);
}

// Round 16
// 387.054 us; speedup vs baseline: 3.7135x; 3.7135x over previous
//
#include <hip/hip_runtime.h>
#include <math.h>

#define LR_C 0.1f
#define WINDOW_C 10
#define NH 512
#define WAVE 64
#define ALPHA (-1.44269504088896340736f)  // -log2(e)
#define NSEG 250
#define KSWEEPS 12   // calibration: K=8 -> 0.109, K=12 -> 0.0078 (NSEG=250)

typedef _Float16 half_t;
typedef __fp16 fp16x2_t __attribute__((ext_vector_type(2)));

__device__ __forceinline__ void gld_lds16(const void* g, void* l) {
    __builtin_amdgcn_global_load_lds((const __attribute__((address_space(1))) void*)g,
                                     (__attribute__((address_space(3))) void*)l, 16, 0, 0);
}
__device__ __forceinline__ void gld_lds4(const void* g, void* l) {
    __builtin_amdgcn_global_load_lds((const __attribute__((address_space(1))) void*)g,
                                     (__attribute__((address_space(3))) void*)l, 4, 0, 0);
}
__device__ __forceinline__ unsigned pack_h2(float a, float b) {
    union { fp16x2_t h; unsigned u; } c;
    c.h = __builtin_amdgcn_cvt_pkrtz(a, b);
    return c.u;
}
__device__ __forceinline__ unsigned pkadd(unsigned a, unsigned b) {
    union { fp16x2_t h; unsigned u; } x, y;
    x.u = a; y.u = b;
    x.h = x.h + y.h;   // v_pk_add_f16
    return x.u;
}
__device__ __forceinline__ float lo_h(unsigned u) {
    union { unsigned short s; half_t h; } c; c.s = (unsigned short)(u & 0xffffu);
    return (float)c.h;
}
__device__ __forceinline__ float hi_h(unsigned u) {
    union { unsigned short s; half_t h; } c; c.s = (unsigned short)(u >> 16);
    return (float)c.h;
}

// Scaled space: W = ALPHA*w, y_t = W[t]·x_t, h_t = 1/(1+2^{y_t}),
// W[t+1] = W[t] + h_t*cx_t,  cx_t = ALPHA*LR*r_t*x_t.
// Lookahead: y_{t+1} = u_t + h_t*d_t,  u_t = W[t]·x_{t+1},  d_t = cx_t·x_{t+1}.
__global__ void prep_kernel(const float* __restrict__ X,
                            const float* __restrict__ rewards,
                            float4* __restrict__ pk, float* __restrict__ dv,
                            int T, int Talloc) {
    int t = blockIdx.x * blockDim.x + threadIdx.x;
    if (t >= Talloc) return;
    if (t >= T) { pk[t] = make_float4(0.f, 0.f, 0.f, 0.f); dv[t] = 0.f; return; }
    int lo = t - (WINDOW_C - 1); if (lo < 0) lo = 0;
    float s = 0.0f;
    for (int k = lo; k <= t; ++k) s += rewards[k];
    float r = rewards[t] - s / (float)(t - lo + 1);
    float c = ALPHA * LR_C * r;
    float cx0 = c * X[2 * t];
    float cx1 = c * X[2 * t + 1];
    float xn0 = 0.0f, xn1 = 0.0f;
    if (t + 1 < T) { xn0 = X[2 * t + 2]; xn1 = X[2 * t + 3]; }
    pk[t] = make_float4(xn0, xn1, cx0, cx1);
    dv[t] = fmaf(cx1, xn1, cx0 * xn0);
}

// Parareal sweep. Block pair (2 blocks) per segment; 256 threads = 4 waves,
// each thread owns one hidden unit. Staging issued FIRST so its latency
// overlaps the prefix-sum prologue (32-deep unrolled -> 32 loads in flight).
// D layout: interleaved [sp][unit] float2 (coalesced). OUT=1: packed-fp16
// shuffle tree + uint4 partial store.
template <int OUT>
__global__ __launch_bounds__(256, 2) void sweep_kernel(
    const float* __restrict__ Wg, const float* __restrict__ X,
    const float4* __restrict__ pk, const float* __restrict__ dv,
    const float* __restrict__ Dread, float* __restrict__ Dwrite,
    int sweep, int L, int Lpad, unsigned* __restrict__ partialU,
    int T, int TW2) {
    extern __shared__ char smem[];
    float4* lpk = (float4*)smem;
    float*  ldv = (float*)(smem + 16 * (size_t)Lpad);

    const int tid  = threadIdx.x;
    const int s    = blockIdx.x >> 1;
    const int half = blockIdx.x & 1;
    const int unit = half * 256 + tid;
    const int lane = tid & 63;
    const int wv   = tid >> 6;
    const int t0   = s * L;

    // stage this segment's operand stream into LDS (issued before prologue;
    // completes while the prefix sum computes)
    for (int k = wv; k * 64 < Lpad; k += 4)
        gld_lds16(pk + t0 + k * 64 + lane, lpk + k * 64);
    for (int k = wv; k * 64 < Lpad; k += 4)
        gld_lds4(dv + t0 + k * 64 + lane, ldv + k * 64);

    float W0 = ALPHA * Wg[2 * unit];
    float W1 = ALPHA * Wg[2 * unit + 1];
    if (sweep > 0) {
        const float2* dp = (const float2*)Dread;
        float acc0[8], acc1[8];
        #pragma unroll
        for (int j = 0; j < 8; ++j) { acc0[j] = 0.f; acc1[j] = 0.f; }
        int sp = 0;
        for (; sp + 32 <= s; sp += 32) {   // 32 independent coalesced loads
            float2 v[32];
            #pragma unroll
            for (int j = 0; j < 32; ++j) v[j] = dp[(size_t)(sp + j) * NH + unit];
            #pragma unroll
            for (int j = 0; j < 32; ++j) { acc0[j & 7] += v[j].x; acc1[j & 7] += v[j].y; }
        }
        for (; sp + 8 <= s; sp += 8) {
            float2 v[8];
            #pragma unroll
            for (int j = 0; j < 8; ++j) v[j] = dp[(size_t)(sp + j) * NH + unit];
            #pragma unroll
            for (int j = 0; j < 8; ++j) { acc0[j] += v[j].x; acc1[j] += v[j].y; }
        }
        for (; sp < s; ++sp) {
            float2 v = dp[(size_t)sp * NH + unit];
            acc0[0] += v.x; acc1[0] += v.y;
        }
        float t00 = 0.f, t01 = 0.f;
        #pragma unroll
        for (int j = 0; j < 8; ++j) { t00 += acc0[j]; t01 += acc1[j]; }
        W0 += t00; W1 += t01;
    }
    const float Wi0 = W0, Wi1 = W1;

    __builtin_amdgcn_s_waitcnt(0);
    __syncthreads();

    float x0 = 0.f, x1 = 0.f;
    if (t0 < T) { x0 = X[2 * t0]; x1 = X[2 * t0 + 1]; }
    float u = fmaf(W1, x1, W0 * x0);     // y at segment-local t=0
    float h = 0.f, dpv = 0.f, cxp0 = 0.f, cxp1 = 0.f;

    const int prow = half * 4 + wv;      // 0..7
    float4 pA[8], pB[8], dA[2], dB[2];
    float hh[8];

#define BODY(Pq, Dq, TT)                                                      \
    {                                                                         \
        _Pragma("unroll")                                                     \
        for (int j = 0; j < 8; ++j) {                                         \
            float y = fmaf(h, dpv, u);                                        \
            W0 = fmaf(h, cxp0, W0);                                           \
            W1 = fmaf(h, cxp1, W1);                                           \
            u = fmaf(W1, Pq[j].y, W0 * Pq[j].x);                              \
            float e = __builtin_amdgcn_exp2f(y);                              \
            h = __builtin_amdgcn_rcpf(1.0f + e);                              \
            hh[j] = h;                                                        \
            cxp0 = Pq[j].z; cxp1 = Pq[j].w; dpv = Dq[j >> 2][j & 3];          \
        }                                                                     \
        if (OUT) {                                                            \
            unsigned pku[4];                                                  \
            _Pragma("unroll")                                                 \
            for (int q = 0; q < 4; ++q)                                       \
                pku[q] = pack_h2(hh[2 * q], hh[2 * q + 1]);                   \
            _Pragma("unroll")                                                 \
            for (int m = 1; m < WAVE; m <<= 1) {                              \
                _Pragma("unroll")                                             \
                for (int q = 0; q < 4; ++q)                                   \
                    pku[q] = pkadd(pku[q], __shfl_xor(pku[q], m, WAVE));      \
            }                                                                 \
            if (lane == 0) {                                                  \
                uint4 st = make_uint4(pku[0], pku[1], pku[2], pku[3]);        \
                *(uint4*)(partialU + (size_t)prow * TW2 + ((t0 + (TT)) >> 1)) = st; \
            }                                                                 \
        }                                                                     \
    }

    #pragma unroll
    for (int j = 0; j < 8; ++j) pA[j] = lpk[j];
    dA[0] = *(float4*)(ldv);     dA[1] = *(float4*)(ldv + 4);
    for (int s0 = 0; s0 < L; s0 += 16) {
        #pragma unroll
        for (int j = 0; j < 8; ++j) pB[j] = lpk[s0 + 8 + j];
        dB[0] = *(float4*)(ldv + s0 + 8); dB[1] = *(float4*)(ldv + s0 + 12);
        BODY(pA, dA, s0)
        if (s0 + 16 < L) {
            #pragma unroll
            for (int j = 0; j < 8; ++j) pA[j] = lpk[s0 + 16 + j];
            dA[0] = *(float4*)(ldv + s0 + 16); dA[1] = *(float4*)(ldv + s0 + 20);
        }
        BODY(pB, dB, s0 + 8)
    }
#undef BODY

    // apply the last step's update -> W at segment end
    W0 = fmaf(h, cxp0, W0);
    W1 = fmaf(h, cxp1, W1);
    if (!OUT) {
        float2* dw = (float2*)Dwrite;
        dw[(size_t)s * NH + unit] = make_float2(W0 - Wi0, W1 - Wi1);
    }
}

// Unpack + sum the 8 packed partial rows; one thread per t-pair.
__global__ void final_packed(const unsigned* __restrict__ pU,
                             float* __restrict__ out, int T, int TW2) {
    int p = blockIdx.x * blockDim.x + threadIdx.x;
    if (p >= (T + 1) / 2) return;
    float s0 = 0.f, s1 = 0.f;
    #pragma unroll
    for (int r = 0; r < 8; ++r) {
        unsigned v = pU[(size_t)r * TW2 + p];
        s0 += lo_h(v);
        s1 += hi_h(v);
    }
    const float inv = 1.0f / (float)NH;
    out[2 * p] = s0 * inv;
    if (2 * p + 1 < T) out[2 * p + 1] = s1 * inv;
}

extern "C" void kernel_launch(void* const* d_in, const int* in_sizes, int n_in,
                              void* d_out, int out_size, void* d_ws, size_t ws_size,
                              hipStream_t stream) {
    const float* X       = (const float*)d_in[0];
    const float* rewards = (const float*)d_in[1];
    const float* Winit   = (const float*)d_in[2];
    float* out = (float*)d_out;
    const int T = in_sizes[1];

    const int L  = (((T + NSEG - 1) / NSEG) + 15) & ~15;  // seg length, %16==0
    const int TW = NSEG * L;                               // padded horizon
    const int TW2 = TW / 2;                                // t-pairs
    const int Lpad = ((L + 63) >> 6) << 6;                 // staged entries
    const int Talloc = TW + Lpad + 64;                     // staging overrun room

    char* w = (char*)d_ws;
    float4*   pk   = (float4*)w;               w += 16ull * (size_t)Talloc;
    float*    dvp  = (float*)w;                w += 4ull * (size_t)Talloc;
    float*    D0   = (float*)w;                w += 4096ull * NSEG;   // 1 MB
    float*    D1   = (float*)w;                w += 4096ull * NSEG;   // 1 MB
    unsigned* partialU = (unsigned*)w;         // 8 * TW2 u32 (~1.6 MB)

    prep_kernel<<<(Talloc + 255) / 256, 256, 0, stream>>>(X, rewards, pk, dvp, T, Talloc);

    const size_t smem = (size_t)Lpad * 20;  // 16B pk + 4B dv per entry
    for (int k = 0; k < KSWEEPS; ++k) {
        const float* Dr = (k & 1) ? D0 : D1;   // written by sweep k-1 (unused at k=0)
        float*       Dw = (k & 1) ? D1 : D0;
        sweep_kernel<0><<<2 * NSEG, 256, smem, stream>>>(
            Winit, X, pk, dvp, Dr, Dw, k, L, Lpad, nullptr, T, TW2);
    }
    sweep_kernel<1><<<2 * NSEG, 256, smem, stream>>>(
        Winit, X, pk, dvp, (KSWEEPS & 1) ? D0 : D1, nullptr,
        KSWEEPS, L, Lpad, partialU, T, TW2);

    final_packed<<<((T + 1) / 2 + 255) / 256, 256, 0, stream>>>(partialU, out, T, TW2);
}

// Round 17
// 381.520 us; speedup vs baseline: 3.7673x; 1.0145x over previous
//
#include <hip/hip_runtime.h>
#include <math.h>

#define LR_C 0.1f
#define WINDOW_C 10
#define NH 512
#define WAVE 64
#define ALPHA (-1.44269504088896340736f)  // -log2(e)
#define NSEG 250
#define KN 6        // Newton-parareal sweeps (exact 2x2 Jacobian, quadratic conv)

typedef _Float16 half_t;
typedef __fp16 fp16x2_t __attribute__((ext_vector_type(2)));

__device__ __forceinline__ void gld_lds16(const void* g, void* l) {
    __builtin_amdgcn_global_load_lds((const __attribute__((address_space(1))) void*)g,
                                     (__attribute__((address_space(3))) void*)l, 16, 0, 0);
}
__device__ __forceinline__ void gld_lds4(const void* g, void* l) {
    __builtin_amdgcn_global_load_lds((const __attribute__((address_space(1))) void*)g,
                                     (__attribute__((address_space(3))) void*)l, 4, 0, 0);
}
__device__ __forceinline__ unsigned pack_h2(float a, float b) {
    union { fp16x2_t h; unsigned u; } c;
    c.h = __builtin_amdgcn_cvt_pkrtz(a, b);
    return c.u;
}
__device__ __forceinline__ unsigned pkadd(unsigned a, unsigned b) {
    union { fp16x2_t h; unsigned u; } x, y;
    x.u = a; y.u = b;
    x.h = x.h + y.h;   // v_pk_add_f16
    return x.u;
}
__device__ __forceinline__ float lo_h(unsigned u) {
    union { unsigned short s; half_t h; } c; c.s = (unsigned short)(u & 0xffffu);
    return (float)c.h;
}
__device__ __forceinline__ float hi_h(unsigned u) {
    union { unsigned short s; half_t h; } c; c.s = (unsigned short)(u >> 16);
    return (float)c.h;
}

// Scaled space: W = ALPHA*w, y_t = W[t]·x_t, h_t = 1/(1+2^{y_t}),
// W[t+1] = W[t] + h_t*cx_t,  cx_t = ALPHA*LR*r_t*x_t.
// Lookahead: y_{t+1} = u_t + h_t*d_t,  u_t = W[t]·x_{t+1},  d_t = cx_t·x_{t+1}.
// Jacobian: J_{t+1} = J_t + cx_t * f'(y_t) * (x_t^T J_t), f'(y) = -ln2*h(1-h).
__global__ void prep_kernel(const float* __restrict__ X,
                            const float* __restrict__ rewards,
                            float4* __restrict__ pk, float* __restrict__ dv,
                            int T, int Talloc) {
    int t = blockIdx.x * blockDim.x + threadIdx.x;
    if (t >= Talloc) return;
    if (t >= T) { pk[t] = make_float4(0.f, 0.f, 0.f, 0.f); dv[t] = 0.f; return; }
    int lo = t - (WINDOW_C - 1); if (lo < 0) lo = 0;
    float s = 0.0f;
    for (int k = lo; k <= t; ++k) s += rewards[k];
    float r = rewards[t] - s / (float)(t - lo + 1);
    float c = ALPHA * LR_C * r;
    float cx0 = c * X[2 * t];
    float cx1 = c * X[2 * t + 1];
    float xn0 = 0.0f, xn1 = 0.0f;
    if (t + 1 < T) { xn0 = X[2 * t + 2]; xn1 = X[2 * t + 3]; }
    pk[t] = make_float4(xn0, xn1, cx0, cx1);
    dv[t] = fmaf(cx1, xn1, cx0 * xn0);
}

// MODE 0: first sweep (inits = ALPHA*Winit), computes Fend+J, records v.
// MODE 1: mid sweep: affine-scan prologue (Newton init), fine+J, Fend+J+v.
// MODE 2: output sweep: affine-scan prologue, fine (no J), packed-fp16 tree.
template <int MODE>
__global__ __launch_bounds__(256, 2) void sweep_kernel(
    const float* __restrict__ Wg, const float* __restrict__ X,
    const float4* __restrict__ pk, const float* __restrict__ dv,
    const float2* __restrict__ vOld, const float2* __restrict__ FendR,
    const float4* __restrict__ JR,
    float2* __restrict__ vNew, float2* __restrict__ FendW,
    float4* __restrict__ JW,
    int L, int Lpad, unsigned* __restrict__ partialU, int T, int TW2) {
    extern __shared__ char smem[];
    float4* lpk = (float4*)smem;
    float*  ldv = (float*)(smem + 16 * (size_t)Lpad);

    const int tid  = threadIdx.x;
    const int s    = blockIdx.x >> 1;
    const int half = blockIdx.x & 1;
    const int unit = half * 256 + tid;
    const int lane = tid & 63;
    const int wv   = tid >> 6;
    const int t0   = s * L;

    // stage operands (issued first; completes while prologue runs)
    for (int k = wv; k * 64 < Lpad; k += 4)
        gld_lds16(pk + t0 + k * 64 + lane, lpk + k * 64);
    for (int k = wv; k * 64 < Lpad; k += 4)
        gld_lds4(dv + t0 + k * 64 + lane, ldv + k * 64);

    float W0, W1;
    if (MODE == 0) {
        W0 = ALPHA * Wg[2 * unit];
        W1 = ALPHA * Wg[2 * unit + 1];
    } else {
        // Newton init: v_s = vOld_s + e_s, e_{sp+1} = (F_sp - vOld_{sp+1}) + J_sp e_sp
        float e0 = 0.f, e1 = 0.f;
        float2 vv = vOld[unit];    // vOld[0][unit]
        int sp = 0;
        for (; sp + 8 <= s; sp += 8) {   // 24 loads in flight per batch
            float2 Fv[8]; float4 Jm[8]; float2 Vn[8];
            #pragma unroll
            for (int q = 0; q < 8; ++q) {
                Fv[q] = FendR[(size_t)(sp + q) * NH + unit];
                Jm[q] = JR[(size_t)(sp + q) * NH + unit];
                Vn[q] = vOld[(size_t)(sp + q + 1) * NH + unit];
            }
            #pragma unroll
            for (int q = 0; q < 8; ++q) {
                float d0 = Fv[q].x - Vn[q].x, d1 = Fv[q].y - Vn[q].y;
                float n0 = fmaf(Jm[q].y, e1, fmaf(Jm[q].x, e0, d0));
                float n1 = fmaf(Jm[q].w, e1, fmaf(Jm[q].z, e0, d1));
                e0 = n0; e1 = n1; vv = Vn[q];
            }
        }
        for (; sp < s; ++sp) {
            float2 Fv = FendR[(size_t)sp * NH + unit];
            float4 Jm = JR[(size_t)sp * NH + unit];
            float2 Vn = vOld[(size_t)(sp + 1) * NH + unit];
            float d0 = Fv.x - Vn.x, d1 = Fv.y - Vn.y;
            float n0 = fmaf(Jm.y, e1, fmaf(Jm.x, e0, d0));
            float n1 = fmaf(Jm.w, e1, fmaf(Jm.z, e0, d1));
            e0 = n0; e1 = n1; vv = Vn;
        }
        W0 = vv.x + e0; W1 = vv.y + e1;
    }
    if (MODE < 2) vNew[(size_t)s * NH + unit] = make_float2(W0, W1);

    __builtin_amdgcn_s_waitcnt(0);
    __syncthreads();

    float x0 = 0.f, x1 = 0.f;
    if (t0 < T) { x0 = X[2 * t0]; x1 = X[2 * t0 + 1]; }
    float u = fmaf(W1, x1, W0 * x0);
    float h = 0.f, dpv = 0.f, cxp0 = 0.f, cxp1 = 0.f;
    float xa0 = 0.f, xa1 = 0.f, xb0 = x0, xb1 = x1;   // x_{t-1}, x_t carries
    float J00 = 1.f, J01 = 0.f, J10 = 0.f, J11 = 1.f;

    const int prow = half * 4 + wv;
    float4 pA[8], pB[8], dA[2], dB[2];
    float hh[8];

#define BODY(Pq, Dq, TT)                                                      \
    {                                                                         \
        _Pragma("unroll")                                                     \
        for (int j = 0; j < 8; ++j) {                                         \
            float y = fmaf(h, dpv, u);                                        \
            if (MODE < 2) {   /* J-update for step t-1 (h,xa,cxp) */          \
                float hm = fmaf(-h, h, h);                                    \
                float g = hm * -0.69314718055994531f;                         \
                float a0 = fmaf(xa1, J10, xa0 * J00);                         \
                float a1 = fmaf(xa1, J11, xa0 * J01);                         \
                float ga0 = g * a0, ga1 = g * a1;                             \
                J00 = fmaf(cxp0, ga0, J00); J01 = fmaf(cxp0, ga1, J01);       \
                J10 = fmaf(cxp1, ga0, J10); J11 = fmaf(cxp1, ga1, J11);       \
            }                                                                 \
            W0 = fmaf(h, cxp0, W0);                                           \
            W1 = fmaf(h, cxp1, W1);                                           \
            u = fmaf(W1, Pq[j].y, W0 * Pq[j].x);                              \
            float e = __builtin_amdgcn_exp2f(y);                              \
            h = __builtin_amdgcn_rcpf(1.0f + e);                              \
            hh[j] = h;                                                        \
            xa0 = xb0; xa1 = xb1; xb0 = Pq[j].x; xb1 = Pq[j].y;               \
            cxp0 = Pq[j].z; cxp1 = Pq[j].w; dpv = Dq[j >> 2][j & 3];          \
        }                                                                     \
        if (MODE == 2) {                                                      \
            unsigned pku[4];                                                  \
            _Pragma("unroll")                                                 \
            for (int q = 0; q < 4; ++q)                                       \
                pku[q] = pack_h2(hh[2 * q], hh[2 * q + 1]);                   \
            _Pragma("unroll")                                                 \
            for (int m = 1; m < WAVE; m <<= 1) {                              \
                _Pragma("unroll")                                             \
                for (int q = 0; q < 4; ++q)                                   \
                    pku[q] = pkadd(pku[q], __shfl_xor(pku[q], m, WAVE));      \
            }                                                                 \
            if (lane == 0) {                                                  \
                uint4 st = make_uint4(pku[0], pku[1], pku[2], pku[3]);        \
                *(uint4*)(partialU + (size_t)prow * TW2 + ((t0 + (TT)) >> 1)) = st; \
            }                                                                 \
        }                                                                     \
    }

    #pragma unroll
    for (int j = 0; j < 8; ++j) pA[j] = lpk[j];
    dA[0] = *(float4*)(ldv);     dA[1] = *(float4*)(ldv + 4);
    for (int s0 = 0; s0 < L; s0 += 16) {
        #pragma unroll
        for (int j = 0; j < 8; ++j) pB[j] = lpk[s0 + 8 + j];
        dB[0] = *(float4*)(ldv + s0 + 8); dB[1] = *(float4*)(ldv + s0 + 12);
        BODY(pA, dA, s0)
        if (s0 + 16 < L) {
            #pragma unroll
            for (int j = 0; j < 8; ++j) pA[j] = lpk[s0 + 16 + j];
            dA[0] = *(float4*)(ldv + s0 + 16); dA[1] = *(float4*)(ldv + s0 + 20);
        }
        BODY(pB, dB, s0 + 8)
    }
#undef BODY

    if (MODE < 2) {
        // final step L-1: J-update uses (h, xb = x_{L-1}, cxp), then W-update
        float hm = fmaf(-h, h, h);
        float g = hm * -0.69314718055994531f;
        float a0 = fmaf(xb1, J10, xb0 * J00);
        float a1 = fmaf(xb1, J11, xb0 * J01);
        float ga0 = g * a0, ga1 = g * a1;
        J00 = fmaf(cxp0, ga0, J00); J01 = fmaf(cxp0, ga1, J01);
        J10 = fmaf(cxp1, ga0, J10); J11 = fmaf(cxp1, ga1, J11);
        W0 = fmaf(h, cxp0, W0);
        W1 = fmaf(h, cxp1, W1);
        FendW[(size_t)s * NH + unit] = make_float2(W0, W1);
        JW[(size_t)s * NH + unit] = make_float4(J00, J01, J10, J11);
    }
}

// Unpack + sum the 8 packed partial rows; one thread per t-pair.
__global__ void final_packed(const unsigned* __restrict__ pU,
                             float* __restrict__ out, int T, int TW2) {
    int p = blockIdx.x * blockDim.x + threadIdx.x;
    if (p >= (T + 1) / 2) return;
    float s0 = 0.f, s1 = 0.f;
    #pragma unroll
    for (int r = 0; r < 8; ++r) {
        unsigned v = pU[(size_t)r * TW2 + p];
        s0 += lo_h(v);
        s1 += hi_h(v);
    }
    const float inv = 1.0f / (float)NH;
    out[2 * p] = s0 * inv;
    if (2 * p + 1 < T) out[2 * p + 1] = s1 * inv;
}

extern "C" void kernel_launch(void* const* d_in, const int* in_sizes, int n_in,
                              void* d_out, int out_size, void* d_ws, size_t ws_size,
                              hipStream_t stream) {
    const float* X       = (const float*)d_in[0];
    const float* rewards = (const float*)d_in[1];
    const float* Winit   = (const float*)d_in[2];
    float* out = (float*)d_out;
    const int T = in_sizes[1];

    const int L  = (((T + NSEG - 1) / NSEG) + 15) & ~15;  // seg length, %16==0
    const int TW = NSEG * L;
    const int TW2 = TW / 2;
    const int Lpad = ((L + 63) >> 6) << 6;
    const int Talloc = TW + Lpad + 64;

    char* w = (char*)d_ws;
    float4*   pk  = (float4*)w;                w += 16ull * (size_t)Talloc;
    float*    dvp = (float*)w;                 w += 4ull * (size_t)Talloc;
    float2*   v0  = (float2*)w;                w += 8ull * NSEG * NH;    // 1 MB
    float2*   v1  = (float2*)w;                w += 8ull * NSEG * NH;
    float2*   F0  = (float2*)w;                w += 8ull * NSEG * NH;
    float2*   F1  = (float2*)w;                w += 8ull * NSEG * NH;
    float4*   J0  = (float4*)w;                w += 16ull * NSEG * NH;   // 2 MB
    float4*   J1  = (float4*)w;                w += 16ull * NSEG * NH;
    unsigned* partialU = (unsigned*)w;         // 8 * TW2 u32 (~1.6 MB)

    prep_kernel<<<(Talloc + 255) / 256, 256, 0, stream>>>(X, rewards, pk, dvp, T, Talloc);

    const size_t smem = (size_t)Lpad * 20;
    // sweep q even writes set0 {v0,F0,J0}, odd writes set1; reads the other.
    sweep_kernel<0><<<2 * NSEG, 256, smem, stream>>>(
        Winit, X, pk, dvp, v1, F1, J1, v0, F0, J0, L, Lpad, nullptr, T, TW2);
    for (int q = 1; q < KN; ++q) {
        const float2* vR = (q & 1) ? v0 : v1;
        const float2* FR = (q & 1) ? F0 : F1;
        const float4* JR = (q & 1) ? J0 : J1;
        float2* vW = (q & 1) ? v1 : v0;
        float2* FW = (q & 1) ? F1 : F0;
        float4* JW = (q & 1) ? J1 : J0;
        sweep_kernel<1><<<2 * NSEG, 256, smem, stream>>>(
            Winit, X, pk, dvp, vR, FR, JR, vW, FW, JW, L, Lpad, nullptr, T, TW2);
    }
    const float2* vR = (KN & 1) ? v1 : v0;   // set written by sweep KN-1
    const float2* FR = (KN & 1) ? F1 : F0;
    const float4* JRp = (KN & 1) ? J1 : J0;
    sweep_kernel<2><<<2 * NSEG, 256, smem, stream>>>(
        Winit, X, pk, dvp, vR, FR, JRp, nullptr, nullptr, nullptr,
        L, Lpad, partialU, T, TW2);

    final_packed<<<((T + 1) / 2 + 255) / 256, 256, 0, stream>>>(partialU, out, T, TW2);
}

// Round 19
// 304.524 us; speedup vs baseline: 4.7199x; 1.2528x over previous
//
#include <hip/hip_runtime.h>
#include <math.h>

#define LR_C 0.1f
#define WINDOW_C 10
#define NH 512
#define WAVE 64
#define ALPHA (-1.44269504088896340736f)  // -log2(e)
#define NSEG 250
#define KN 6   // Newton sweeps (J recomputed every sweep; R17-calibrated)

typedef _Float16 half_t;
typedef __fp16 fp16x2_t __attribute__((ext_vector_type(2)));

__device__ __forceinline__ void gld_lds16(const void* g, void* l) {
    __builtin_amdgcn_global_load_lds((const __attribute__((address_space(1))) void*)g,
                                     (__attribute__((address_space(3))) void*)l, 16, 0, 0);
}
__device__ __forceinline__ void gld_lds4(const void* g, void* l) {
    __builtin_amdgcn_global_load_lds((const __attribute__((address_space(1))) void*)g,
                                     (__attribute__((address_space(3))) void*)l, 4, 0, 0);
}
__device__ __forceinline__ unsigned pack_h2(float a, float b) {
    union { fp16x2_t h; unsigned u; } c;
    c.h = __builtin_amdgcn_cvt_pkrtz(a, b);
    return c.u;
}
__device__ __forceinline__ unsigned pkadd(unsigned a, unsigned b) {
    union { fp16x2_t h; unsigned u; } x, y;
    x.u = a; y.u = b;
    x.h = x.h + y.h;   // v_pk_add_f16
    return x.u;
}
__device__ __forceinline__ float lo_h(unsigned u) {
    union { unsigned short s; half_t h; } c; c.s = (unsigned short)(u & 0xffffu);
    return (float)c.h;
}
__device__ __forceinline__ float hi_h(unsigned u) {
    union { unsigned short s; half_t h; } c; c.s = (unsigned short)(u >> 16);
    return (float)c.h;
}

// Scaled space: W = ALPHA*w, y_t = W[t]·x_t, h_t = 1/(1+2^{y_t}),
// W[t+1] = W[t] + h_t*cx_t,  cx_t = ALPHA*LR*r_t*x_t.
// Lookahead: y_{t+1} = u_t + h_t*d_t,  u_t = W[t]·x_{t+1},  d_t = cx_t·x_{t+1}.
// Jacobian: J_{t+1} = J_t + cx_t * f'(y_t) * (x_t^T J_t), f'(y) = -ln2*h(1-h).
__global__ void prep_kernel(const float* __restrict__ X,
                            const float* __restrict__ rewards,
                            float4* __restrict__ pk, float* __restrict__ dv,
                            int T, int Talloc) {
    int t = blockIdx.x * blockDim.x + threadIdx.x;
    if (t >= Talloc) return;
    if (t >= T) { pk[t] = make_float4(0.f, 0.f, 0.f, 0.f); dv[t] = 0.f; return; }
    int lo = t - (WINDOW_C - 1); if (lo < 0) lo = 0;
    float s = 0.0f;
    for (int k = lo; k <= t; ++k) s += rewards[k];
    float r = rewards[t] - s / (float)(t - lo + 1);
    float c = ALPHA * LR_C * r;
    float cx0 = c * X[2 * t];
    float cx1 = c * X[2 * t + 1];
    float xn0 = 0.0f, xn1 = 0.0f;
    if (t + 1 < T) { xn0 = X[2 * t + 2]; xn1 = X[2 * t + 3]; }
    pk[t] = make_float4(xn0, xn1, cx0, cx1);
    dv[t] = fmaf(cx1, xn1, cx0 * xn0);
}

// MODE 0: v = uniform ALPHA*Winit (written to vbuf); fine WITH J; writes F,J.
// MODE 1: v from vbuf (one load); fine WITH J (true Newton); writes F,J.
// MODE 2: v from vbuf; linear fine; packed-fp16 OUT tree.
template <int MODE>
__global__ __launch_bounds__(256, 2) void sweep_kernel(
    const float* __restrict__ Wg, const float* __restrict__ X,
    const float4* __restrict__ pk, const float* __restrict__ dv,
    float2* __restrict__ vbuf, float2* __restrict__ Fbuf,
    float4* __restrict__ Jbuf,
    int L, int Lpad, unsigned* __restrict__ partialU, int T, int TW2) {
    extern __shared__ char smem[];
    float4* lpk = (float4*)smem;
    float*  ldv = (float*)(smem + 16 * (size_t)Lpad);

    const int tid  = threadIdx.x;
    const int s    = blockIdx.x >> 1;
    const int half = blockIdx.x & 1;
    const int unit = half * 256 + tid;
    const int lane = tid & 63;
    const int wv   = tid >> 6;
    const int t0   = s * L;

    // stage operands (issued first; completes during init)
    for (int k = wv; k * 64 < Lpad; k += 4)
        gld_lds16(pk + t0 + k * 64 + lane, lpk + k * 64);
    for (int k = wv; k * 64 < Lpad; k += 4)
        gld_lds4(dv + t0 + k * 64 + lane, ldv + k * 64);

    float W0, W1;
    if (MODE == 0) {
        W0 = ALPHA * Wg[2 * unit];
        W1 = ALPHA * Wg[2 * unit + 1];
        vbuf[(size_t)s * NH + unit] = make_float2(W0, W1);
    } else {
        float2 vv = vbuf[(size_t)s * NH + unit];
        W0 = vv.x; W1 = vv.y;
    }

    __builtin_amdgcn_s_waitcnt(0);
    __syncthreads();

    float x0 = 0.f, x1 = 0.f;
    if (t0 < T) { x0 = X[2 * t0]; x1 = X[2 * t0 + 1]; }
    float u = fmaf(W1, x1, W0 * x0);
    float h = 0.f, dpv = 0.f, cxp0 = 0.f, cxp1 = 0.f;
    float xa0 = 0.f, xa1 = 0.f, xb0 = x0, xb1 = x1;   // x_{t-1}, x_t carries
    float J00 = 1.f, J01 = 0.f, J10 = 0.f, J11 = 1.f;

    const int prow = half * 4 + wv;
    float4 pA[8], pB[8], dA[2], dB[2];
    float hh[8];

#define BODY(Pq, Dq, TT)                                                      \
    {                                                                         \
        _Pragma("unroll")                                                     \
        for (int j = 0; j < 8; ++j) {                                         \
            float y = fmaf(h, dpv, u);                                        \
            if (MODE < 2) {   /* J-update for step t-1 (h,xa,cxp) */          \
                float hm = fmaf(-h, h, h);                                    \
                float g = hm * -0.69314718055994531f;                         \
                float a0 = fmaf(xa1, J10, xa0 * J00);                         \
                float a1 = fmaf(xa1, J11, xa0 * J01);                         \
                float ga0 = g * a0, ga1 = g * a1;                             \
                J00 = fmaf(cxp0, ga0, J00); J01 = fmaf(cxp0, ga1, J01);       \
                J10 = fmaf(cxp1, ga0, J10); J11 = fmaf(cxp1, ga1, J11);       \
            }                                                                 \
            W0 = fmaf(h, cxp0, W0);                                           \
            W1 = fmaf(h, cxp1, W1);                                           \
            u = fmaf(W1, Pq[j].y, W0 * Pq[j].x);                              \
            float e = __builtin_amdgcn_exp2f(y);                              \
            h = __builtin_amdgcn_rcpf(1.0f + e);                              \
            hh[j] = h;                                                        \
            xa0 = xb0; xa1 = xb1; xb0 = Pq[j].x; xb1 = Pq[j].y;               \
            cxp0 = Pq[j].z; cxp1 = Pq[j].w; dpv = Dq[j >> 2][j & 3];          \
        }                                                                     \
        if (MODE == 2) {                                                      \
            unsigned pku[4];                                                  \
            _Pragma("unroll")                                                 \
            for (int q = 0; q < 4; ++q)                                       \
                pku[q] = pack_h2(hh[2 * q], hh[2 * q + 1]);                   \
            _Pragma("unroll")                                                 \
            for (int m = 1; m < WAVE; m <<= 1) {                              \
                _Pragma("unroll")                                             \
                for (int q = 0; q < 4; ++q)                                   \
                    pku[q] = pkadd(pku[q], __shfl_xor(pku[q], m, WAVE));      \
            }                                                                 \
            if (lane == 0) {                                                  \
                uint4 st = make_uint4(pku[0], pku[1], pku[2], pku[3]);        \
                *(uint4*)(partialU + (size_t)prow * TW2 + ((t0 + (TT)) >> 1)) = st; \
            }                                                                 \
        }                                                                     \
    }

    #pragma unroll
    for (int j = 0; j < 8; ++j) pA[j] = lpk[j];
    dA[0] = *(float4*)(ldv);     dA[1] = *(float4*)(ldv + 4);
    for (int s0 = 0; s0 < L; s0 += 16) {
        #pragma unroll
        for (int j = 0; j < 8; ++j) pB[j] = lpk[s0 + 8 + j];
        dB[0] = *(float4*)(ldv + s0 + 8); dB[1] = *(float4*)(ldv + s0 + 12);
        BODY(pA, dA, s0)
        if (s0 + 16 < L) {
            #pragma unroll
            for (int j = 0; j < 8; ++j) pA[j] = lpk[s0 + 16 + j];
            dA[0] = *(float4*)(ldv + s0 + 16); dA[1] = *(float4*)(ldv + s0 + 20);
        }
        BODY(pB, dB, s0 + 8)
    }
#undef BODY

    if (MODE < 2) {
        // step L-1 J-update: after the loop, xa = x_{L-1} (NOT xb = x_L)
        float hm = fmaf(-h, h, h);
        float g = hm * -0.69314718055994531f;
        float a0 = fmaf(xa1, J10, xa0 * J00);
        float a1 = fmaf(xa1, J11, xa0 * J01);
        float ga0 = g * a0, ga1 = g * a1;
        J00 = fmaf(cxp0, ga0, J00); J01 = fmaf(cxp0, ga1, J01);
        J10 = fmaf(cxp1, ga0, J10); J11 = fmaf(cxp1, ga1, J11);
        Jbuf[(size_t)s * NH + unit] = make_float4(J00, J01, J10, J11);
        W0 = fmaf(h, cxp0, W0);
        W1 = fmaf(h, cxp1, W1);
        Fbuf[(size_t)s * NH + unit] = make_float2(W0, W1);
    }
}

// Parallel affine scan (Hillis-Steele) over segments, one block per unit.
// Step i (i<NSEG-1): e_{i+1} = J_i e_i + (F_i - v_{i+1}), e_0 = 0.
// Composition (own=later ∘ earlier): A = A_i A_p, b = A_i b_p + b_i.
// After inclusive scan, element i holds e_{i+1}; update v[i+1] += e_{i+1}.
__global__ __launch_bounds__(256) void scan_kernel(
    float2* __restrict__ vbuf, const float2* __restrict__ Fbuf,
    const float4* __restrict__ Jbuf) {
    __shared__ float4 As[256];
    __shared__ float2 bs[256];
    const int i = threadIdx.x;
    const int u = blockIdx.x;
    float2 vnext = make_float2(0.f, 0.f);
    if (i < NSEG - 1) {
        float4 Jm = Jbuf[(size_t)i * NH + u];
        float2 Fv = Fbuf[(size_t)i * NH + u];
        vnext = vbuf[(size_t)(i + 1) * NH + u];
        As[i] = Jm;
        bs[i] = make_float2(Fv.x - vnext.x, Fv.y - vnext.y);
    } else {
        As[i] = make_float4(1.f, 0.f, 0.f, 1.f);
        bs[i] = make_float2(0.f, 0.f);
    }
    __syncthreads();
    #pragma unroll
    for (int off = 1; off < 256; off <<= 1) {
        float4 Ai = As[i]; float2 bi = bs[i];
        float4 Ap = make_float4(1.f, 0.f, 0.f, 1.f);
        float2 bp = make_float2(0.f, 0.f);
        const bool act = (i >= off);
        if (act) { Ap = As[i - off]; bp = bs[i - off]; }
        __syncthreads();
        if (act) {
            float4 C;
            C.x = fmaf(Ai.y, Ap.z, Ai.x * Ap.x);
            C.y = fmaf(Ai.y, Ap.w, Ai.x * Ap.y);
            C.z = fmaf(Ai.w, Ap.z, Ai.z * Ap.x);
            C.w = fmaf(Ai.w, Ap.w, Ai.z * Ap.y);
            float2 nb;
            nb.x = fmaf(Ai.y, bp.y, fmaf(Ai.x, bp.x, bi.x));
            nb.y = fmaf(Ai.w, bp.y, fmaf(Ai.z, bp.x, bi.y));
            As[i] = C; bs[i] = nb;
        }
        __syncthreads();
    }
    if (i < NSEG - 1) {
        float2 e = bs[i];
        vbuf[(size_t)(i + 1) * NH + u] = make_float2(vnext.x + e.x, vnext.y + e.y);
    }
}

// Unpack + sum the 8 packed partial rows; one thread per t-pair.
__global__ void final_packed(const unsigned* __restrict__ pU,
                             float* __restrict__ out, int T, int TW2) {
    int p = blockIdx.x * blockDim.x + threadIdx.x;
    if (p >= (T + 1) / 2) return;
    float s0 = 0.f, s1 = 0.f;
    #pragma unroll
    for (int r = 0; r < 8; ++r) {
        unsigned v = pU[(size_t)r * TW2 + p];
        s0 += lo_h(v);
        s1 += hi_h(v);
    }
    const float inv = 1.0f / (float)NH;
    out[2 * p] = s0 * inv;
    if (2 * p + 1 < T) out[2 * p + 1] = s1 * inv;
}

extern "C" void kernel_launch(void* const* d_in, const int* in_sizes, int n_in,
                              void* d_out, int out_size, void* d_ws, size_t ws_size,
                              hipStream_t stream) {
    const float* X       = (const float*)d_in[0];
    const float* rewards = (const float*)d_in[1];
    const float* Winit   = (const float*)d_in[2];
    float* out = (float*)d_out;
    const int T = in_sizes[1];

    const int L  = (((T + NSEG - 1) / NSEG) + 15) & ~15;  // seg length, %16==0
    const int TW = NSEG * L;
    const int TW2 = TW / 2;
    const int Lpad = ((L + 63) >> 6) << 6;
    const int Talloc = TW + Lpad + 64;

    char* w = (char*)d_ws;
    float4*   pk  = (float4*)w;                w += 16ull * (size_t)Talloc;
    float*    dvp = (float*)w;                 w += 4ull * (size_t)Talloc;
    float2*   v   = (float2*)w;                w += 8ull * NSEG * NH;    // 1 MB
    float2*   F   = (float2*)w;                w += 8ull * NSEG * NH;    // 1 MB
    float4*   J   = (float4*)w;                w += 16ull * NSEG * NH;   // 2 MB
    unsigned* partialU = (unsigned*)w;         // 8 * TW2 u32 (~1.6 MB)

    prep_kernel<<<(Talloc + 255) / 256, 256, 0, stream>>>(X, rewards, pk, dvp, T, Talloc);

    const size_t smem = (size_t)Lpad * 20;
    // true Newton: every sweep recomputes F and J at the current inits,
    // then the parallel affine scan applies the exact linearized correction.
    sweep_kernel<0><<<2 * NSEG, 256, smem, stream>>>(
        Winit, X, pk, dvp, v, F, J, L, Lpad, nullptr, T, TW2);
    scan_kernel<<<NH, 256, 0, stream>>>(v, F, J);
    for (int q = 1; q < KN; ++q) {
        sweep_kernel<1><<<2 * NSEG, 256, smem, stream>>>(
            Winit, X, pk, dvp, v, F, J, L, Lpad, nullptr, T, TW2);
        scan_kernel<<<NH, 256, 0, stream>>>(v, F, J);
    }
    sweep_kernel<2><<<2 * NSEG, 256, smem, stream>>>(
        Winit, X, pk, dvp, v, F, J, L, Lpad, partialU, T, TW2);

    final_packed<<<((T + 1) / 2 + 255) / 256, 256, 0, stream>>>(partialU, out, T, TW2);
}

// Round 21
// 289.441 us; speedup vs baseline: 4.9658x; 1.0521x over previous
//
#include <hip/hip_runtime.h>
#include <math.h>

#define LR_C 0.1f
#define WINDOW_C 10
#define NH 512
#define WAVE 64
#define ALPHA (-1.44269504088896340736f)  // -log2(e)
#define NSEG 250
#define KN 6   // Newton sweeps; calibration: KN=4 -> 0.080 FAIL, KN=6 -> 0.0039 floor

typedef _Float16 half_t;
typedef __fp16 fp16x2_t __attribute__((ext_vector_type(2)));

__device__ __forceinline__ void gld_lds16(const void* g, void* l) {
    __builtin_amdgcn_global_load_lds((const __attribute__((address_space(1))) void*)g,
                                     (__attribute__((address_space(3))) void*)l, 16, 0, 0);
}
__device__ __forceinline__ void gld_lds4(const void* g, void* l) {
    __builtin_amdgcn_global_load_lds((const __attribute__((address_space(1))) void*)g,
                                     (__attribute__((address_space(3))) void*)l, 4, 0, 0);
}
__device__ __forceinline__ unsigned pack_h2(float a, float b) {
    union { fp16x2_t h; unsigned u; } c;
    c.h = __builtin_amdgcn_cvt_pkrtz(a, b);
    return c.u;
}
__device__ __forceinline__ unsigned pkadd(unsigned a, unsigned b) {
    union { fp16x2_t h; unsigned u; } x, y;
    x.u = a; y.u = b;
    x.h = x.h + y.h;   // v_pk_add_f16
    return x.u;
}
__device__ __forceinline__ float lo_h(unsigned u) {
    union { unsigned short s; half_t h; } c; c.s = (unsigned short)(u & 0xffffu);
    return (float)c.h;
}
__device__ __forceinline__ float hi_h(unsigned u) {
    union { unsigned short s; half_t h; } c; c.s = (unsigned short)(u >> 16);
    return (float)c.h;
}

// Scaled space: W = ALPHA*w, y_t = W[t]·x_t, h_t = 1/(1+2^{y_t}),
// W[t+1] = W[t] + h_t*cx_t,  cx_t = ALPHA*LR*r_t*x_t.
// Lookahead: y_{t+1} = u_t + h_t*d_t,  u_t = W[t]·x_{t+1},  d_t = cx_t·x_{t+1}.
// Jacobian: J_{t+1} = J_t + cx_t * f'(y_t) * (x_t^T J_t), f'(y) = -ln2*h(1-h).
__global__ void prep_kernel(const float* __restrict__ X,
                            const float* __restrict__ rewards,
                            float4* __restrict__ pk, float* __restrict__ dv,
                            int T, int Talloc) {
    int t = blockIdx.x * blockDim.x + threadIdx.x;
    if (t >= Talloc) return;
    if (t >= T) { pk[t] = make_float4(0.f, 0.f, 0.f, 0.f); dv[t] = 0.f; return; }
    int lo = t - (WINDOW_C - 1); if (lo < 0) lo = 0;
    float s = 0.0f;
    for (int k = lo; k <= t; ++k) s += rewards[k];
    float r = rewards[t] - s / (float)(t - lo + 1);
    float c = ALPHA * LR_C * r;
    float cx0 = c * X[2 * t];
    float cx1 = c * X[2 * t + 1];
    float xn0 = 0.0f, xn1 = 0.0f;
    if (t + 1 < T) { xn0 = X[2 * t + 2]; xn1 = X[2 * t + 3]; }
    pk[t] = make_float4(xn0, xn1, cx0, cx1);
    dv[t] = fmaf(cx1, xn1, cx0 * xn0);
}

// MODE 0: v = uniform ALPHA*Winit (written to vbuf); fine WITH J; writes F,J.
// MODE 1: v from vbuf; fine WITH J (true Newton); writes F,J.
// MODE 2: v from vbuf; linear fine; packed-fp16 OUT tree.
// MODE 3: v from vbuf; linear fine; writes F only (final chord correction).
template <int MODE>
__global__ __launch_bounds__(256, 2) void sweep_kernel(
    const float* __restrict__ Wg, const float* __restrict__ X,
    const float4* __restrict__ pk, const float* __restrict__ dv,
    float2* __restrict__ vbuf, float2* __restrict__ Fbuf,
    float4* __restrict__ Jbuf,
    int L, int Lpad, unsigned* __restrict__ partialU, int T, int TW2) {
    extern __shared__ char smem[];
    float4* lpk = (float4*)smem;
    float*  ldv = (float*)(smem + 16 * (size_t)Lpad);

    const int tid  = threadIdx.x;
    const int s    = blockIdx.x >> 1;
    const int half = blockIdx.x & 1;
    const int unit = half * 256 + tid;
    const int lane = tid & 63;
    const int wv   = tid >> 6;
    const int t0   = s * L;
    const bool WITHJ = (MODE == 0 || MODE == 1);

    // stage operands (issued first; completes during init)
    for (int k = wv; k * 64 < Lpad; k += 4)
        gld_lds16(pk + t0 + k * 64 + lane, lpk + k * 64);
    for (int k = wv; k * 64 < Lpad; k += 4)
        gld_lds4(dv + t0 + k * 64 + lane, ldv + k * 64);

    float W0, W1;
    if (MODE == 0) {
        W0 = ALPHA * Wg[2 * unit];
        W1 = ALPHA * Wg[2 * unit + 1];
        vbuf[(size_t)s * NH + unit] = make_float2(W0, W1);
    } else {
        float2 vv = vbuf[(size_t)s * NH + unit];
        W0 = vv.x; W1 = vv.y;
    }

    __builtin_amdgcn_s_waitcnt(0);
    __syncthreads();

    float x0 = 0.f, x1 = 0.f;
    if (t0 < T) { x0 = X[2 * t0]; x1 = X[2 * t0 + 1]; }
    float u = fmaf(W1, x1, W0 * x0);
    float h = 0.f, dpv = 0.f, cxp0 = 0.f, cxp1 = 0.f;
    float xa0 = 0.f, xa1 = 0.f, xb0 = x0, xb1 = x1;   // x_{t-1}, x_t carries
    float J00 = 1.f, J01 = 0.f, J10 = 0.f, J11 = 1.f;

    const int prow = half * 4 + wv;
    float4 pA[8], pB[8], dA[2], dB[2];
    float hh[8];

#define BODY(Pq, Dq, TT)                                                      \
    {                                                                         \
        _Pragma("unroll")                                                     \
        for (int j = 0; j < 8; ++j) {                                         \
            float y = fmaf(h, dpv, u);                                        \
            if (WITHJ) {   /* J-update for step t-1 (h,xa,cxp) */             \
                float hm = fmaf(-h, h, h);                                    \
                float g = hm * -0.69314718055994531f;                         \
                float a0 = fmaf(xa1, J10, xa0 * J00);                         \
                float a1 = fmaf(xa1, J11, xa0 * J01);                         \
                float ga0 = g * a0, ga1 = g * a1;                             \
                J00 = fmaf(cxp0, ga0, J00); J01 = fmaf(cxp0, ga1, J01);       \
                J10 = fmaf(cxp1, ga0, J10); J11 = fmaf(cxp1, ga1, J11);       \
            }                                                                 \
            W0 = fmaf(h, cxp0, W0);                                           \
            W1 = fmaf(h, cxp1, W1);                                           \
            u = fmaf(W1, Pq[j].y, W0 * Pq[j].x);                              \
            float e = __builtin_amdgcn_exp2f(y);                              \
            h = __builtin_amdgcn_rcpf(1.0f + e);                              \
            hh[j] = h;                                                        \
            xa0 = xb0; xa1 = xb1; xb0 = Pq[j].x; xb1 = Pq[j].y;               \
            cxp0 = Pq[j].z; cxp1 = Pq[j].w; dpv = Dq[j >> 2][j & 3];          \
        }                                                                     \
        if (MODE == 2) {                                                      \
            unsigned pku[4];                                                  \
            _Pragma("unroll")                                                 \
            for (int q = 0; q < 4; ++q)                                       \
                pku[q] = pack_h2(hh[2 * q], hh[2 * q + 1]);                   \
            _Pragma("unroll")                                                 \
            for (int m = 1; m < WAVE; m <<= 1) {                              \
                _Pragma("unroll")                                             \
                for (int q = 0; q < 4; ++q)                                   \
                    pku[q] = pkadd(pku[q], __shfl_xor(pku[q], m, WAVE));      \
            }                                                                 \
            if (lane == 0) {                                                  \
                uint4 st = make_uint4(pku[0], pku[1], pku[2], pku[3]);        \
                *(uint4*)(partialU + (size_t)prow * TW2 + ((t0 + (TT)) >> 1)) = st; \
            }                                                                 \
        }                                                                     \
    }

    #pragma unroll
    for (int j = 0; j < 8; ++j) pA[j] = lpk[j];
    dA[0] = *(float4*)(ldv);     dA[1] = *(float4*)(ldv + 4);
    for (int s0 = 0; s0 < L; s0 += 16) {
        #pragma unroll
        for (int j = 0; j < 8; ++j) pB[j] = lpk[s0 + 8 + j];
        dB[0] = *(float4*)(ldv + s0 + 8); dB[1] = *(float4*)(ldv + s0 + 12);
        BODY(pA, dA, s0)
        if (s0 + 16 < L) {
            #pragma unroll
            for (int j = 0; j < 8; ++j) pA[j] = lpk[s0 + 16 + j];
            dA[0] = *(float4*)(ldv + s0 + 16); dA[1] = *(float4*)(ldv + s0 + 20);
        }
        BODY(pB, dB, s0 + 8)
    }
#undef BODY

    if (MODE != 2) {
        if (WITHJ) {
            // step L-1 J-update: after the loop, xa = x_{L-1}
            float hm = fmaf(-h, h, h);
            float g = hm * -0.69314718055994531f;
            float a0 = fmaf(xa1, J10, xa0 * J00);
            float a1 = fmaf(xa1, J11, xa0 * J01);
            float ga0 = g * a0, ga1 = g * a1;
            J00 = fmaf(cxp0, ga0, J00); J01 = fmaf(cxp0, ga1, J01);
            J10 = fmaf(cxp1, ga0, J10); J11 = fmaf(cxp1, ga1, J11);
            Jbuf[(size_t)s * NH + unit] = make_float4(J00, J01, J10, J11);
        }
        W0 = fmaf(h, cxp0, W0);
        W1 = fmaf(h, cxp1, W1);
        Fbuf[(size_t)s * NH + unit] = make_float2(W0, W1);
    }
}

// Parallel affine scan (Hillis-Steele) over segments, one block per unit.
// Step i (i<NSEG-1): e_{i+1} = J_i e_i + (F_i - v_{i+1}), e_0 = 0.
// After inclusive scan, element i holds e_{i+1}; update v[i+1] += e_{i+1}.
__global__ __launch_bounds__(256) void scan_kernel(
    float2* __restrict__ vbuf, const float2* __restrict__ Fbuf,
    const float4* __restrict__ Jbuf) {
    __shared__ float4 As[256];
    __shared__ float2 bs[256];
    const int i = threadIdx.x;
    const int u = blockIdx.x;
    float2 vnext = make_float2(0.f, 0.f);
    if (i < NSEG - 1) {
        float4 Jm = Jbuf[(size_t)i * NH + u];
        float2 Fv = Fbuf[(size_t)i * NH + u];
        vnext = vbuf[(size_t)(i + 1) * NH + u];
        As[i] = Jm;
        bs[i] = make_float2(Fv.x - vnext.x, Fv.y - vnext.y);
    } else {
        As[i] = make_float4(1.f, 0.f, 0.f, 1.f);
        bs[i] = make_float2(0.f, 0.f);
    }
    __syncthreads();
    #pragma unroll
    for (int off = 1; off < 256; off <<= 1) {
        float4 Ai = As[i]; float2 bi = bs[i];
        float4 Ap = make_float4(1.f, 0.f, 0.f, 1.f);
        float2 bp = make_float2(0.f, 0.f);
        const bool act = (i >= off);
        if (act) { Ap = As[i - off]; bp = bs[i - off]; }
        __syncthreads();
        if (act) {
            float4 C;
            C.x = fmaf(Ai.y, Ap.z, Ai.x * Ap.x);
            C.y = fmaf(Ai.y, Ap.w, Ai.x * Ap.y);
            C.z = fmaf(Ai.w, Ap.z, Ai.z * Ap.x);
            C.w = fmaf(Ai.w, Ap.w, Ai.z * Ap.y);
            float2 nb;
            nb.x = fmaf(Ai.y, bp.y, fmaf(Ai.x, bp.x, bi.x));
            nb.y = fmaf(Ai.w, bp.y, fmaf(Ai.z, bp.x, bi.y));
            As[i] = C; bs[i] = nb;
        }
        __syncthreads();
    }
    if (i < NSEG - 1) {
        float2 e = bs[i];
        vbuf[(size_t)(i + 1) * NH + u] = make_float2(vnext.x + e.x, vnext.y + e.y);
    }
}

// Unpack + sum the 8 packed partial rows; one thread per t-pair.
__global__ void final_packed(const unsigned* __restrict__ pU,
                             float* __restrict__ out, int T, int TW2) {
    int p = blockIdx.x * blockDim.x + threadIdx.x;
    if (p >= (T + 1) / 2) return;
    float s0 = 0.f, s1 = 0.f;
    #pragma unroll
    for (int r = 0; r < 8; ++r) {
        unsigned v = pU[(size_t)r * TW2 + p];
        s0 += lo_h(v);
        s1 += hi_h(v);
    }
    const float inv = 1.0f / (float)NH;
    out[2 * p] = s0 * inv;
    if (2 * p + 1 < T) out[2 * p + 1] = s1 * inv;
}

extern "C" void kernel_launch(void* const* d_in, const int* in_sizes, int n_in,
                              void* d_out, int out_size, void* d_ws, size_t ws_size,
                              hipStream_t stream) {
    const float* X       = (const float*)d_in[0];
    const float* rewards = (const float*)d_in[1];
    const float* Winit   = (const float*)d_in[2];
    float* out = (float*)d_out;
    const int T = in_sizes[1];

    const int L  = (((T + NSEG - 1) / NSEG) + 15) & ~15;  // seg length, %16==0
    const int TW = NSEG * L;
    const int TW2 = TW / 2;
    const int Lpad = ((L + 63) >> 6) << 6;
    const int Talloc = TW + Lpad + 64;

    char* w = (char*)d_ws;
    float4*   pk  = (float4*)w;                w += 16ull * (size_t)Talloc;
    float*    dvp = (float*)w;                 w += 4ull * (size_t)Talloc;
    float2*   v   = (float2*)w;                w += 8ull * NSEG * NH;    // 1 MB
    float2*   F   = (float2*)w;                w += 8ull * NSEG * NH;    // 1 MB
    float4*   J   = (float4*)w;                w += 16ull * NSEG * NH;   // 2 MB
    unsigned* partialU = (unsigned*)w;         // 8 * TW2 u32 (~1.6 MB)

    prep_kernel<<<(Talloc + 255) / 256, 256, 0, stream>>>(X, rewards, pk, dvp, T, Talloc);

    const size_t smem = (size_t)Lpad * 20;
    // true Newton sweeps 0..KN-2 (fresh J each); final correction (KN-1) is a
    // lite sweep (F only) whose scan reuses the previous sweep's J — a chord
    // step at near-convergence (second-order error).
    sweep_kernel<0><<<2 * NSEG, 256, smem, stream>>>(
        Winit, X, pk, dvp, v, F, J, L, Lpad, nullptr, T, TW2);
    scan_kernel<<<NH, 256, 0, stream>>>(v, F, J);
    for (int q = 1; q < KN - 1; ++q) {
        sweep_kernel<1><<<2 * NSEG, 256, smem, stream>>>(
            Winit, X, pk, dvp, v, F, J, L, Lpad, nullptr, T, TW2);
        scan_kernel<<<NH, 256, 0, stream>>>(v, F, J);
    }
    sweep_kernel<3><<<2 * NSEG, 256, smem, stream>>>(
        Winit, X, pk, dvp, v, F, J, L, Lpad, nullptr, T, TW2);
    scan_kernel<<<NH, 256, 0, stream>>>(v, F, J);
    sweep_kernel<2><<<2 * NSEG, 256, smem, stream>>>(
        Winit, X, pk, dvp, v, F, J, L, Lpad, partialU, T, TW2);

    final_packed<<<((T + 1) / 2 + 255) / 256, 256, 0, stream>>>(partialU, out, T, TW2);
}